// Round 2
// baseline (8944.994 us; speedup 1.0000x reference)
//
#include <hip/hip_runtime.h>
#include <hip/hip_bf16.h>

// Problem dims
#define Bb    128
#define Ss    256
#define Ff    4
#define Vv    1024
#define Ee    512
#define Hh    1024
#define FourH 4096
#define Mrows (Bb * Ss)   // 32768

typedef _Float16 f16;
typedef __attribute__((ext_vector_type(8))) _Float16 half8;
typedef __attribute__((ext_vector_type(4))) float f32x4;

// ---------------------------------------------------------------------------
// fp32 -> fp16 convert (grid-stride)
__global__ void cvt_f16_kernel(const float* __restrict__ s, f16* __restrict__ d, int n) {
    int i = blockIdx.x * blockDim.x + threadIdx.x;
    int stride = gridDim.x * blockDim.x;
    for (; i < n; i += stride) d[i] = (f16)s[i];
}

// bias0 = b_ih0 + b_hh0 ; bias1 = b_ih1 + b_hh1
__global__ void bias_combine_kernel(const float* __restrict__ a, const float* __restrict__ b,
                                    const float* __restrict__ c, const float* __restrict__ d,
                                    float* __restrict__ o0, float* __restrict__ o1) {
    int i = blockIdx.x * blockDim.x + threadIdx.x;
    if (i < FourH) o0[i] = a[i] + b[i];
    else if (i < 2 * FourH) { int j = i - FourH; o1[j] = c[j] + d[j]; }
}

// ---------------------------------------------------------------------------
// Embedding: sum over F tables -> f16 [S, B, E]  (TIME-MAJOR: row = s*B + b)
__global__ void emb_kernel(const int* __restrict__ x, const float* __restrict__ emb,
                           f16* __restrict__ out) {
    int r = blockIdx.x;           // 0..32767  (= b*S + s, input layout)
    int t = threadIdx.x;          // 256
    int b = r / Ss, s = r % Ss;
    const int* xr = x + (size_t)r * Ff;
    int i0 = xr[0], i1 = xr[1], i2 = xr[2], i3 = xr[3];
    const float* e0 = emb + (size_t)i0 * Ee;
    const float* e1 = emb + (size_t)(Vv + i1) * Ee;
    const float* e2 = emb + (size_t)(2 * Vv + i2) * Ee;
    const float* e3 = emb + (size_t)(3 * Vv + i3) * Ee;
    f16* orow = out + (size_t)(s * Bb + b) * Ee;   // time-major write
    for (int e = t; e < Ee; e += 256) {
        float sum = e0[e] + e1[e] + e2[e] + e3[e];
        orow[e] = (f16)sum;
    }
}

// ---------------------------------------------------------------------------
// C[M,N] = A[M,K] @ B[N,K]^T + bias[N], all f16 in / f16 out, fp32 accum.
// 128x128 tile, 256 threads (4 waves, each 64x64 = 4x4 MFMA 16x16x32 tiles).
#define BM 128
#define BN 128
#define BK 32
#define LDP 40   // padded LDS K-stride (elements): 80B rows -> 16B-aligned frag reads

__global__ __launch_bounds__(256) void gemm_bt_kernel(
    const f16* __restrict__ A, const f16* __restrict__ Bw,
    const float* __restrict__ bias, f16* __restrict__ C,
    int M, int N, int K)
{
    __shared__ f16 As[BM * LDP];
    __shared__ f16 Bs[BN * LDP];
    int tid  = threadIdx.x;
    int n0   = blockIdx.x * BN;
    int m0   = blockIdx.y * BM;
    int w    = tid >> 6, lane = tid & 63;
    int wm   = (w >> 1) * 64, wn = (w & 1) * 64;
    int lrow = lane & 15, koff = lane >> 4;

    f32x4 acc[4][4] = {};

    for (int kb = 0; kb < K; kb += BK) {
        __syncthreads();
        #pragma unroll
        for (int h = 0; h < 2; ++h) {
            int ch  = tid + h * 256;          // 512 chunks of 8 elems per matrix
            int row = ch >> 2;
            int cc  = (ch & 3) * 8;
            *reinterpret_cast<uint4*>(&As[row * LDP + cc]) =
                *reinterpret_cast<const uint4*>(A + (size_t)(m0 + row) * K + kb + cc);
            *reinterpret_cast<uint4*>(&Bs[row * LDP + cc]) =
                *reinterpret_cast<const uint4*>(Bw + (size_t)(n0 + row) * K + kb + cc);
        }
        __syncthreads();
        half8 af[4], bf[4];
        #pragma unroll
        for (int mt = 0; mt < 4; ++mt)
            af[mt] = *reinterpret_cast<const half8*>(&As[(wm + mt * 16 + lrow) * LDP + koff * 8]);
        #pragma unroll
        for (int nt = 0; nt < 4; ++nt)
            bf[nt] = *reinterpret_cast<const half8*>(&Bs[(wn + nt * 16 + lrow) * LDP + koff * 8]);
        #pragma unroll
        for (int mt = 0; mt < 4; ++mt)
            #pragma unroll
            for (int nt = 0; nt < 4; ++nt)
                acc[mt][nt] = __builtin_amdgcn_mfma_f32_16x16x32_f16(af[mt], bf[nt], acc[mt][nt], 0, 0, 0);
    }

    #pragma unroll
    for (int mt = 0; mt < 4; ++mt) {
        #pragma unroll
        for (int nt = 0; nt < 4; ++nt) {
            int col = n0 + wn + nt * 16 + lrow;
            float bv = bias[col];
            #pragma unroll
            for (int r = 0; r < 4; ++r) {
                int rowg = m0 + wm + mt * 16 + koff * 4 + r;
                C[(size_t)rowg * N + col] = (f16)(acc[mt][nt][r] + bv);
            }
        }
    }
}

// ---------------------------------------------------------------------------
// One LSTM timestep: gates = gates_x[t] + h_prev @ W^T, then cell update.
// 256 blocks x 512 threads. Block handles 4 hidden units (16 gate cols).
// 8 waves: waves 0-3 take K[0,512), waves 4-7 take K[512,1024); LDS reduce.
template <int MODE>   // 0: also write f16 h0_seq slice; 1: write fp32 d_out slice
__global__ __launch_bounds__(512) void lstm_step_kernel(
    const f16* __restrict__ gx,     // [128, 4096] this timestep (biases included)
    const f16* __restrict__ hp,     // [128, 1024] previous h (f16)
    const f16* __restrict__ Wh,     // [4096, 1024] f16
    float* __restrict__ c,          // [128, 1024] cell state (in/out)
    f16* __restrict__ ho,           // [128, 1024] new h (f16)
    f16* __restrict__ hseq,         // MODE 0 target
    float* __restrict__ fo)         // MODE 1 target: d_out + t*H, row stride S*H
{
    __shared__ float preA[128][17];
    __shared__ float preB[128][17];
    int tid  = threadIdx.x;
    int u0   = blockIdx.x * 4;
    int w    = tid >> 6, lane = tid & 63;
    int ksec = w >> 2;              // 0 or 1 -> K half
    int wm   = (w & 3) * 32;        // 32 batch rows per wave (2 M-tiles)
    int lrow = lane & 15, koff = lane >> 4;
    int n    = lrow;                            // 0..15 tile col
    int j    = (n >> 2) * Hh + u0 + (n & 3);    // gate column: gate g = n>>2, unit uu = n&3

    const f16* wr  = Wh + (size_t)j * Hh + ksec * 512;
    const f16* ar0 = hp + (size_t)(wm + lrow) * Hh + ksec * 512;
    const f16* ar1 = ar0 + (size_t)16 * Hh;

    f32x4 acc0 = {0.f, 0.f, 0.f, 0.f}, acc1 = {0.f, 0.f, 0.f, 0.f};
    for (int k = 0; k < 512; k += 32) {
        half8 b  = *reinterpret_cast<const half8*>(wr  + k + koff * 8);
        half8 a0 = *reinterpret_cast<const half8*>(ar0 + k + koff * 8);
        half8 a1 = *reinterpret_cast<const half8*>(ar1 + k + koff * 8);
        acc0 = __builtin_amdgcn_mfma_f32_16x16x32_f16(a0, b, acc0, 0, 0, 0);
        acc1 = __builtin_amdgcn_mfma_f32_16x16x32_f16(a1, b, acc1, 0, 0, 0);
    }

    float (*dst)[17] = ksec ? preB : preA;
    #pragma unroll
    for (int r = 0; r < 4; ++r) {
        int row = wm + koff * 4 + r;
        float g0 = acc0[r], g1 = acc1[r];
        if (ksec == 0) {
            g0 += (float)gx[(size_t)row * FourH + j];
            g1 += (float)gx[(size_t)(row + 16) * FourH + j];
        }
        dst[row][n]      = g0;
        dst[row + 16][n] = g1;
    }
    __syncthreads();

    // 512 (row, unit) pairs, one per thread
    int row = tid >> 2, uu = tid & 3;
    float ip = preA[row][uu]      + preB[row][uu];
    float fp = preA[row][4 + uu]  + preB[row][4 + uu];
    float gp = preA[row][8 + uu]  + preB[row][8 + uu];
    float op = preA[row][12 + uu] + preB[row][12 + uu];
    float si = 1.f / (1.f + expf(-ip));
    float sf = 1.f / (1.f + expf(-fp));
    float so = 1.f / (1.f + expf(-op));
    float tg = tanhf(gp);
    int u = u0 + uu;
    size_t ci = (size_t)row * Hh + u;
    float cn = sf * c[ci] + si * tg;
    c[ci] = cn;
    float hn = so * tanhf(cn);
    f16 hh = (f16)hn;
    ho[ci] = hh;
    if (MODE == 0) hseq[ci] = hh;
    else           fo[(size_t)row * (Ss * Hh) + u] = hn;
}

// ---------------------------------------------------------------------------
extern "C" void kernel_launch(void* const* d_in, const int* in_sizes, int n_in,
                              void* d_out, int out_size, void* d_ws, size_t ws_size,
                              hipStream_t stream) {
    const int*   x      = (const int*)  d_in[0];
    const float* emb    = (const float*)d_in[1];
    const float* proj_w = (const float*)d_in[2];
    const float* proj_b = (const float*)d_in[3];
    const float* W_ih0  = (const float*)d_in[4];
    const float* W_hh0  = (const float*)d_in[5];
    const float* b_ih0  = (const float*)d_in[6];
    const float* b_hh0  = (const float*)d_in[7];
    const float* W_ih1  = (const float*)d_in[8];
    const float* W_hh1  = (const float*)d_in[9];
    const float* b_ih1  = (const float*)d_in[10];
    const float* b_hh1  = (const float*)d_in[11];
    float* out = (float*)d_out;

    // Workspace layout (~223 MB)
    char* ws = (char*)d_ws;
    f16* emb_sum = (f16*)(ws + 0);                       // 32 MB  [S,B,E]
    f16* x_in    = (f16*)(ws + 33554432);                // 32 MB  [S,B,E]
    f16* gates   = (f16*)(ws + 67108864);                // 64 MB (chunk of 64 steps)
    f16* h0_seq  = (f16*)(ws + 134217728);               // 64 MB [S,B,H]
    char* wp     = ws + 201326592;
    f16* pw_f   = (f16*)wp; wp += (size_t)Ee * Ee * 2;           // 512 KB
    f16* wih0_f = (f16*)wp; wp += (size_t)FourH * Ee * 2;        // 4 MB
    f16* whh0_f = (f16*)wp; wp += (size_t)FourH * Hh * 2;        // 8 MB
    f16* wih1_f = (f16*)wp; wp += (size_t)FourH * Hh * 2;        // 8 MB
    f16* whh1_f = (f16*)wp; wp += (size_t)FourH * Hh * 2;        // 8 MB
    float* bias0 = (float*)wp; wp += FourH * 4;
    float* bias1 = (float*)wp; wp += FourH * 4;
    char* zbase = wp;
    f16*   h0A = (f16*)wp;   wp += (size_t)Bb * Hh * 2;
    float* c0  = (float*)wp; wp += (size_t)Bb * Hh * 4;
    f16*   h1A = (f16*)wp;   wp += (size_t)Bb * Hh * 2;
    float* c1  = (float*)wp; wp += (size_t)Bb * Hh * 4;
    size_t zbytes = (size_t)(wp - zbase);
    f16* h0B = (f16*)wp; wp += (size_t)Bb * Hh * 2;
    f16* h1B = (f16*)wp; wp += (size_t)Bb * Hh * 2;

    // 1. Weight conversions + combined biases + zero states
    cvt_f16_kernel<<<512, 256, 0, stream>>>(proj_w, pw_f,   Ee * Ee);
    cvt_f16_kernel<<<512, 256, 0, stream>>>(W_ih0,  wih0_f, FourH * Ee);
    cvt_f16_kernel<<<512, 256, 0, stream>>>(W_hh0,  whh0_f, FourH * Hh);
    cvt_f16_kernel<<<512, 256, 0, stream>>>(W_ih1,  wih1_f, FourH * Hh);
    cvt_f16_kernel<<<512, 256, 0, stream>>>(W_ih1,  wih1_f, FourH * Hh);
    cvt_f16_kernel<<<512, 256, 0, stream>>>(W_hh1,  whh1_f, FourH * Hh);
    bias_combine_kernel<<<32, 256, 0, stream>>>(b_ih0, b_hh0, b_ih1, b_hh1, bias0, bias1);
    hipMemsetAsync(zbase, 0, zbytes, stream);

    // 2. Embedding sum -> emb_sum  [S,B,E] time-major
    emb_kernel<<<Mrows, 256, 0, stream>>>(x, emb, emb_sum);

    // 3. x_in = emb_sum @ proj_w^T + proj_b   [S*B, E] time-major
    gemm_bt_kernel<<<dim3(Ee / BN, Mrows / BM), 256, 0, stream>>>(
        emb_sum, pw_f, proj_b, x_in, Mrows, Ee, Ee);

    // 4. Layer 0: chunked gates GEMM + scan
    f16* h0p[2] = {h0A, h0B};
    for (int ck = 0; ck < 4; ++ck) {
        const int CM = Mrows / 4;  // 8192 rows = 64 steps x 128 batch (time-major)
        gemm_bt_kernel<<<dim3(FourH / BN, CM / BM), 256, 0, stream>>>(
            x_in + (size_t)ck * CM * Ee, wih0_f, bias0, gates, CM, FourH, Ee);
        for (int tt = 0; tt < 64; ++tt) {
            int t = ck * 64 + tt;
            lstm_step_kernel<0><<<256, 512, 0, stream>>>(
                gates + (size_t)tt * Bb * FourH,
                h0p[t & 1], whh0_f, c0, h0p[(t + 1) & 1],
                h0_seq + (size_t)t * Bb * Hh, nullptr);
        }
    }

    // 5. Layer 1: chunked gates GEMM (input = h0_seq) + scan -> d_out
    f16* h1p[2] = {h1A, h1B};
    for (int ck = 0; ck < 4; ++ck) {
        const int CM = Mrows / 4;
        gemm_bt_kernel<<<dim3(FourH / BN, CM / BM), 256, 0, stream>>>(
            h0_seq + (size_t)ck * CM * Hh, wih1_f, bias1, gates, CM, FourH, Hh);
        for (int tt = 0; tt < 64; ++tt) {
            int t = ck * 64 + tt;
            lstm_step_kernel<1><<<256, 512, 0, stream>>>(
                gates + (size_t)tt * Bb * FourH,
                h1p[t & 1], whh1_f, c1, h1p[(t + 1) & 1],
                nullptr, out + (size_t)t * Hh);
        }
    }
}

// Round 3
// 7612.321 us; speedup vs baseline: 1.1751x; 1.1751x over previous
//
#include <hip/hip_runtime.h>
#include <hip/hip_bf16.h>

#define Bb    128
#define Ss    256
#define Ff    4
#define Vv    1024
#define Ee    512
#define Hh    1024
#define FourH 4096
#define Mrows (Bb * Ss)
#define NBLK  192      // 64 layer-0 WGs + 128 layer-1 WGs

typedef _Float16 f16;
typedef __attribute__((ext_vector_type(8))) _Float16 half8;
typedef __attribute__((ext_vector_type(4))) float f32x4;

// ---------------------------------------------------------------------------
__global__ void cvt_f16_kernel(const float* __restrict__ s, f16* __restrict__ d, int n) {
    int i = blockIdx.x * blockDim.x + threadIdx.x;
    int stride = gridDim.x * blockDim.x;
    for (; i < n; i += stride) d[i] = (f16)s[i];
}

__global__ void bias_combine_kernel(const float* __restrict__ a, const float* __restrict__ b,
                                    const float* __restrict__ c, const float* __restrict__ d,
                                    float* __restrict__ o0, float* __restrict__ o1) {
    int i = blockIdx.x * blockDim.x + threadIdx.x;
    if (i < FourH) o0[i] = a[i] + b[i];
    else if (i < 2 * FourH) { int j = i - FourH; o1[j] = c[j] + d[j]; }
}

// Embedding: sum over F tables -> f16 [S, B, E] (time-major)
__global__ void emb_kernel(const int* __restrict__ x, const float* __restrict__ emb,
                           f16* __restrict__ out) {
    int r = blockIdx.x;
    int t = threadIdx.x;
    int b = r / Ss, s = r % Ss;
    const int* xr = x + (size_t)r * Ff;
    const float* e0 = emb + (size_t)xr[0] * Ee;
    const float* e1 = emb + (size_t)(Vv + xr[1]) * Ee;
    const float* e2 = emb + (size_t)(2 * Vv + xr[2]) * Ee;
    const float* e3 = emb + (size_t)(3 * Vv + xr[3]) * Ee;
    f16* orow = out + (size_t)(s * Bb + b) * Ee;
    for (int e = t; e < Ee; e += 256) orow[e] = (f16)(e0[e] + e1[e] + e2[e] + e3[e]);
}

// ---------------------------------------------------------------------------
// C[M,N] = A[M,K] @ B[N,K]^T + bias[N]  (f16 in, f16 out, fp32 accum)
#define BM 128
#define BN 128
#define BK 32
#define LDP 40

__global__ __launch_bounds__(256) void gemm_bt_kernel(
    const f16* __restrict__ A, const f16* __restrict__ Bw,
    const float* __restrict__ bias, f16* __restrict__ C,
    int M, int N, int K)
{
    __shared__ f16 As[BM * LDP];
    __shared__ f16 Bs[BN * LDP];
    int tid  = threadIdx.x;
    int n0   = blockIdx.x * BN;
    int m0   = blockIdx.y * BM;
    int w    = tid >> 6, lane = tid & 63;
    int wm   = (w >> 1) * 64, wn = (w & 1) * 64;
    int lrow = lane & 15, koff = lane >> 4;

    f32x4 acc[4][4] = {};

    for (int kb = 0; kb < K; kb += BK) {
        __syncthreads();
        #pragma unroll
        for (int h = 0; h < 2; ++h) {
            int ch  = tid + h * 256;
            int row = ch >> 2;
            int cc  = (ch & 3) * 8;
            *reinterpret_cast<uint4*>(&As[row * LDP + cc]) =
                *reinterpret_cast<const uint4*>(A + (size_t)(m0 + row) * K + kb + cc);
            *reinterpret_cast<uint4*>(&Bs[row * LDP + cc]) =
                *reinterpret_cast<const uint4*>(Bw + (size_t)(n0 + row) * K + kb + cc);
        }
        __syncthreads();
        half8 af[4], bf[4];
        #pragma unroll
        for (int mt = 0; mt < 4; ++mt)
            af[mt] = *reinterpret_cast<const half8*>(&As[(wm + mt * 16 + lrow) * LDP + koff * 8]);
        #pragma unroll
        for (int nt = 0; nt < 4; ++nt)
            bf[nt] = *reinterpret_cast<const half8*>(&Bs[(wn + nt * 16 + lrow) * LDP + koff * 8]);
        #pragma unroll
        for (int mt = 0; mt < 4; ++mt)
            #pragma unroll
            for (int nt = 0; nt < 4; ++nt)
                acc[mt][nt] = __builtin_amdgcn_mfma_f32_16x16x32_f16(af[mt], bf[nt], acc[mt][nt], 0, 0, 0);
    }

    #pragma unroll
    for (int mt = 0; mt < 4; ++mt)
        #pragma unroll
        for (int nt = 0; nt < 4; ++nt) {
            int col = n0 + wn + nt * 16 + lrow;
            float bv = bias[col];
            #pragma unroll
            for (int r = 0; r < 4; ++r) {
                int rowg = m0 + wm + mt * 16 + koff * 4 + r;
                C[(size_t)rowg * N + col] = (f16)(acc[mt][nt][r] + bv);
            }
        }
}

// ---------------------------------------------------------------------------
// Monotonic device-scope grid barrier (cooperative launch guarantees residency)
__device__ __forceinline__ void grid_sync(unsigned* bar) {
    __syncthreads();
    if (threadIdx.x == 0) {
        __threadfence();
        unsigned my = atomicAdd(&bar[0], 1u);
        unsigned target = my / NBLK + 1u;
        if (my % NBLK == NBLK - 1u) atomicAdd(&bar[1], 1u);
        while (atomicAdd(&bar[1], 0u) < target) __builtin_amdgcn_s_sleep(2);
        __threadfence();
    }
    __syncthreads();
}

__device__ __forceinline__ float sigm(float v) { return 1.f / (1.f + __expf(-v)); }

// ---------------------------------------------------------------------------
// Persistent fused 2-layer LSTM scan. Iteration i: L0 computes step i (i<256),
// L1 computes step i-1 (i>=1). Weights held in VGPRs for the whole launch.
// WGs 0..63: L0, 16 units each. WGs 64..191: L1, 8 units each (K=2048).
__global__ __launch_bounds__(512, 2) void scan_kernel(
    const f16* __restrict__ gx0,    // gates0 chunk base [nt][128][4096]
    int t_begin, int t_end,
    const f16* __restrict__ wih1, const f16* __restrict__ whh0,
    const f16* __restrict__ whh1, const float* __restrict__ bias1,
    f16* __restrict__ h0a, f16* __restrict__ h0b,
    f16* __restrict__ h1a, f16* __restrict__ h1b,
    float* __restrict__ c0, float* __restrict__ c1,
    float* __restrict__ out, unsigned* __restrict__ bar)
{
    __shared__ f16 st[2][128 * 136];           // 69.6 KB: staging (+ epilogue reuse)
    float* ep = (float*)&st[0][0];

    const int tid  = threadIdx.x;
    const int wg   = blockIdx.x;
    const int lane = tid & 63;
    const int lrow = lane & 15, koff = lane >> 4;
    const int w    = tid >> 6;

    if (wg < 64) {
        // ---------------- Layer 0: 16 units, K=1024 ----------------
        const int u0 = wg * 16;
        const int m  = w & 1;          // row half: 64 rows
        const int g  = w >> 1;         // gate 0..3 (16 cols each)
        const int wm = m * 64;
        half8 wreg[32];
        {
            const f16* wr = whh0 + (size_t)(g * Hh + u0 + lrow) * Hh + koff * 8;
            #pragma unroll
            for (int kt = 0; kt < 32; ++kt) wreg[kt] = *(const half8*)(wr + kt * 32);
        }
        float creg[4];
        #pragma unroll
        for (int q = 0; q < 4; ++q) {
            int p = tid + q * 512; int row = p >> 4, uu = p & 15;
            creg[q] = c0[row * Hh + u0 + uu];
        }
        for (int i = t_begin; i < t_end; ++i) {
            if (i < 256) {
                const f16* hp = (i & 1) ? h0a : h0b;   // h0[i-1]
                f16*       hw = (i & 1) ? h0b : h0a;   // h0[i]
                f32x4 acc[4] = {};
                #pragma unroll
                for (int ck = 0; ck < 8; ++ck) {
                    __syncthreads();
                    #pragma unroll
                    for (int ps = 0; ps < 4; ++ps) {
                        int unit = ps * 512 + tid;
                        int row = unit >> 4, seg = unit & 15;
                        *(uint4*)&st[0][row * 136 + seg * 8] =
                            *(const uint4*)(hp + row * Hh + ck * 128 + seg * 8);
                    }
                    __syncthreads();
                    #pragma unroll
                    for (int kt2 = 0; kt2 < 4; ++kt2)
                        #pragma unroll
                        for (int mt = 0; mt < 4; ++mt) {
                            half8 a = *(const half8*)&st[0][(wm + mt * 16 + lrow) * 136 + kt2 * 32 + koff * 8];
                            acc[mt] = __builtin_amdgcn_mfma_f32_16x16x32_f16(a, wreg[ck * 4 + kt2], acc[mt], 0, 0, 0);
                        }
                }
                __syncthreads();
                // ep[g][row][u], row stride 20 floats (bank-friendly)
                #pragma unroll
                for (int mt = 0; mt < 4; ++mt)
                    #pragma unroll
                    for (int r = 0; r < 4; ++r)
                        ep[g * 2560 + (wm + mt * 16 + koff * 4 + r) * 20 + lrow] = acc[mt][r];
                __syncthreads();
                const f16* gx = gx0 + (size_t)(i - t_begin) * (Bb * FourH);
                #pragma unroll
                for (int q = 0; q < 4; ++q) {
                    int p = tid + q * 512; int row = p >> 4, uu = p & 15;
                    float ipre = ep[0 * 2560 + row * 20 + uu] + (float)gx[row * FourH + u0 + uu];
                    float fpre = ep[1 * 2560 + row * 20 + uu] + (float)gx[row * FourH + Hh + u0 + uu];
                    float gpre = ep[2 * 2560 + row * 20 + uu] + (float)gx[row * FourH + 2 * Hh + u0 + uu];
                    float opre = ep[3 * 2560 + row * 20 + uu] + (float)gx[row * FourH + 3 * Hh + u0 + uu];
                    float cn = sigm(fpre) * creg[q] + sigm(ipre) * tanhf(gpre);
                    creg[q] = cn;
                    hw[row * Hh + u0 + uu] = (f16)(sigm(opre) * tanhf(cn));
                }
            }
            grid_sync(bar);
        }
        #pragma unroll
        for (int q = 0; q < 4; ++q) {
            int p = tid + q * 512; int row = p >> 4, uu = p & 15;
            c0[row * Hh + u0 + uu] = creg[q];
        }
    } else {
        // ---------------- Layer 1: 8 units, K=2048 ([wih1; whh1]) ----------------
        const int wgl = wg - 64;
        const int u0  = wgl * 8;
        const int n    = w >> 2;          // col group 0..1 (16 cols = 2 gates)
        const int m    = (w >> 1) & 1;    // row half
        const int ksec = w & 1;           // K half: 0=ih (h0[t]), 1=hh (h1[t-1])
        const int wm   = m * 64;
        const int gcol = n * 2 + (lrow >> 3);   // gate 0..3
        const int ucol = lrow & 7;
        half8 wreg[32];
        {
            const f16* wr = (ksec ? whh1 : wih1) + (size_t)(gcol * Hh + u0 + ucol) * Hh + koff * 8;
            #pragma unroll
            for (int kt = 0; kt < 32; ++kt) wreg[kt] = *(const half8*)(wr + kt * 32);
        }
        float creg[2];
        #pragma unroll
        for (int q = 0; q < 2; ++q) {
            int p = tid + q * 512; int row = p >> 3, uu = p & 7;
            creg[q] = c1[row * Hh + u0 + uu];
        }
        for (int i = t_begin; i < t_end; ++i) {
            int t1 = i - 1;
            if (t1 >= 0) {
                const f16* a0 = (t1 & 1) ? h0b : h0a;  // h0[t1]
                const f16* a1 = (t1 & 1) ? h1a : h1b;  // h1[t1-1]
                f16*       hw = (t1 & 1) ? h1b : h1a;  // h1[t1]
                f32x4 acc[4] = {};
                #pragma unroll
                for (int ck = 0; ck < 8; ++ck) {
                    __syncthreads();
                    #pragma unroll
                    for (int ps = 0; ps < 8; ++ps) {
                        int idx = ps * 512 + tid;
                        int buf = idx >> 11;
                        int rs  = idx & 2047;
                        int row = rs >> 4, seg = rs & 15;
                        *(uint4*)&st[buf][row * 136 + seg * 8] =
                            *(const uint4*)((buf ? a1 : a0) + row * Hh + ck * 128 + seg * 8);
                    }
                    __syncthreads();
                    #pragma unroll
                    for (int kt2 = 0; kt2 < 4; ++kt2)
                        #pragma unroll
                        for (int mt = 0; mt < 4; ++mt) {
                            half8 a = *(const half8*)&st[ksec][(wm + mt * 16 + lrow) * 136 + kt2 * 32 + koff * 8];
                            acc[mt] = __builtin_amdgcn_mfma_f32_16x16x32_f16(a, wreg[ck * 4 + kt2], acc[mt], 0, 0, 0);
                        }
                }
                __syncthreads();
                // ep[ksec][g][row][u], row stride 9 floats
                #pragma unroll
                for (int mt = 0; mt < 4; ++mt)
                    #pragma unroll
                    for (int r = 0; r < 4; ++r)
                        ep[ksec * 4608 + gcol * 1152 + (wm + mt * 16 + koff * 4 + r) * 9 + ucol] = acc[mt][r];
                __syncthreads();
                #pragma unroll
                for (int q = 0; q < 2; ++q) {
                    int p = tid + q * 512; int row = p >> 3, uu = p & 7;
                    int ug = u0 + uu;
                    float ipre = ep[0 * 1152 + row * 9 + uu] + ep[4608 + 0 * 1152 + row * 9 + uu] + bias1[ug];
                    float fpre = ep[1 * 1152 + row * 9 + uu] + ep[4608 + 1 * 1152 + row * 9 + uu] + bias1[Hh + ug];
                    float gpre = ep[2 * 1152 + row * 9 + uu] + ep[4608 + 2 * 1152 + row * 9 + uu] + bias1[2 * Hh + ug];
                    float opre = ep[3 * 1152 + row * 9 + uu] + ep[4608 + 3 * 1152 + row * 9 + uu] + bias1[3 * Hh + ug];
                    float cn = sigm(fpre) * creg[q] + sigm(ipre) * tanhf(gpre);
                    creg[q] = cn;
                    float hn = sigm(opre) * tanhf(cn);
                    hw[row * Hh + ug] = (f16)hn;
                    out[(size_t)row * (Ss * Hh) + (size_t)t1 * Hh + ug] = hn;
                }
            }
            grid_sync(bar);
        }
        #pragma unroll
        for (int q = 0; q < 2; ++q) {
            int p = tid + q * 512; int row = p >> 3, uu = p & 7;
            c1[row * Hh + u0 + uu] = creg[q];
        }
    }
}

// ---------------------------------------------------------------------------
extern "C" void kernel_launch(void* const* d_in, const int* in_sizes, int n_in,
                              void* d_out, int out_size, void* d_ws, size_t ws_size,
                              hipStream_t stream) {
    const int*   x      = (const int*)  d_in[0];
    const float* emb    = (const float*)d_in[1];
    const float* proj_w = (const float*)d_in[2];
    const float* proj_b = (const float*)d_in[3];
    const float* W_ih0  = (const float*)d_in[4];
    const float* W_hh0  = (const float*)d_in[5];
    const float* b_ih0  = (const float*)d_in[6];
    const float* b_hh0  = (const float*)d_in[7];
    const float* W_ih1  = (const float*)d_in[8];
    const float* W_hh1  = (const float*)d_in[9];
    const float* b_ih1  = (const float*)d_in[10];
    const float* b_hh1  = (const float*)d_in[11];
    float* out = (float*)d_out;

    char* ws = (char*)d_ws;
    f16* emb_sum = (f16*)(ws);                               // 32 MB [S,B,E]
    f16* x_in    = (f16*)(ws + 33554432ull);                 // 32 MB [S,B,E]
    f16* gates   = (f16*)(ws + 67108864ull);                 // 128 MB (128-step chunk)
    char* wp     = ws + 201326592ull;
    f16* pw_f   = (f16*)wp; wp += (size_t)Ee * Ee * 2;
    f16* wih0_f = (f16*)wp; wp += (size_t)FourH * Ee * 2;
    f16* whh0_f = (f16*)wp; wp += (size_t)FourH * Hh * 2;
    f16* wih1_f = (f16*)wp; wp += (size_t)FourH * Hh * 2;
    f16* whh1_f = (f16*)wp; wp += (size_t)FourH * Hh * 2;
    float* bias0 = (float*)wp; wp += FourH * 4;
    float* bias1 = (float*)wp; wp += FourH * 4;
    char* zbase = wp;
    f16*   h0a = (f16*)wp;   wp += (size_t)Bb * Hh * 2;
    f16*   h0b = (f16*)wp;   wp += (size_t)Bb * Hh * 2;
    f16*   h1a = (f16*)wp;   wp += (size_t)Bb * Hh * 2;
    f16*   h1b = (f16*)wp;   wp += (size_t)Bb * Hh * 2;
    float* c0  = (float*)wp; wp += (size_t)Bb * Hh * 4;
    float* c1  = (float*)wp; wp += (size_t)Bb * Hh * 4;
    unsigned* bar = (unsigned*)wp; wp += 256;
    size_t zbytes = (size_t)(wp - zbase);

    // Prologue: converts, biases, zero state+barrier
    cvt_f16_kernel<<<512, 256, 0, stream>>>(proj_w, pw_f,   Ee * Ee);
    cvt_f16_kernel<<<512, 256, 0, stream>>>(W_ih0,  wih0_f, FourH * Ee);
    cvt_f16_kernel<<<512, 256, 0, stream>>>(W_hh0,  whh0_f, FourH * Hh);
    cvt_f16_kernel<<<512, 256, 0, stream>>>(W_ih1,  wih1_f, FourH * Hh);
    cvt_f16_kernel<<<512, 256, 0, stream>>>(W_hh1,  whh1_f, FourH * Hh);
    bias_combine_kernel<<<32, 256, 0, stream>>>(b_ih0, b_hh0, b_ih1, b_hh1, bias0, bias1);
    hipMemsetAsync(zbase, 0, zbytes, stream);

    // Embedding + input projection (time-major)
    emb_kernel<<<Mrows, 256, 0, stream>>>(x, emb, emb_sum);
    gemm_bt_kernel<<<dim3(Ee / BN, Mrows / BM), 256, 0, stream>>>(
        emb_sum, pw_f, proj_b, x_in, Mrows, Ee, Ee);

    // Two half-sequence passes: gates0 GEMM chunk + cooperative scan
    const int CM = Mrows / 2;   // 16384 rows = 128 steps
    int m_ = Mrows, n4 = FourH, kE = Ee, kH = Hh; (void)m_; (void)n4; (void)kE; (void)kH;

    for (int half = 0; half < 2; ++half) {
        gemm_bt_kernel<<<dim3(FourH / BN, CM / BM), 256, 0, stream>>>(
            x_in + (size_t)half * CM * Ee, wih0_f, bias0, gates, CM, FourH, Ee);
        int tb = half * 128;
        int te = (half == 0) ? 128 : 257;   // second pass runs one extra L1-only iter
        const f16* gxp = gates;
        void* args[] = { (void*)&gxp, (void*)&tb, (void*)&te,
                         (void*)&wih1_f, (void*)&whh0_f, (void*)&whh1_f, (void*)&bias1,
                         (void*)&h0a, (void*)&h0b, (void*)&h1a, (void*)&h1b,
                         (void*)&c0, (void*)&c1, (void*)&out, (void*)&bar };
        hipLaunchCooperativeKernel((const void*)scan_kernel, dim3(NBLK), dim3(512),
                                   args, 0, stream);
    }
}